// Round 7
// baseline (62.421 us; speedup 1.0000x reference)
//
#include <hip/hip_runtime.h>

#define NB 8
#define NS 2048
#define ND 128
#define NK 16

typedef float f32x4 __attribute__((ext_vector_type(4)));

// ---- cross-lane partner fetch (lane ^ KIND) ----
template <int KIND>
__device__ inline int partner_i32(int v) {
    if constexpr (KIND == 1) {
        return __builtin_amdgcn_update_dpp(0, v, 0xB1, 0xF, 0xF, true);   // quad_perm xor1
    } else if constexpr (KIND == 2) {
        return __builtin_amdgcn_update_dpp(0, v, 0x4E, 0xF, 0xF, true);   // quad_perm xor2
    } else if constexpr (KIND == 32) {
        return __shfl_xor(v, 32, 64);
    } else {
        constexpr int imm = (KIND << 10) | 0x1F;                          // ds_swizzle BitMode
        return __builtin_amdgcn_ds_swizzle(v, imm);
    }
}
template <int KIND>
__device__ inline float partner_f32(float v) {
    return __int_as_float(partner_i32<KIND>(__float_as_int(v)));
}
template <int KIND>
__device__ inline double partner_f64(double v) {
    const long long x = __double_as_longlong(v);
    const int lo = partner_i32<KIND>((int)(unsigned int)x);
    const int hi = partner_i32<KIND>((int)(x >> 32));
    return __longlong_as_double(((long long)hi << 32) | (unsigned int)lo);
}
__device__ inline float partner_f32_dyn(float v, int d) {
    switch (d) {
    case 1:  return partner_f32<1>(v);
    case 2:  return partner_f32<2>(v);
    case 4:  return partner_f32<4>(v);
    case 8:  return partner_f32<8>(v);
    case 16: return partner_f32<16>(v);
    default: return partner_f32<32>(v);
    }
}
__device__ inline double partner_f64_dyn(double v, int d) {
    switch (d) {
    case 1:  return partner_f64<1>(v);
    case 2:  return partner_f64<2>(v);
    case 4:  return partner_f64<4>(v);
    case 8:  return partner_f64<8>(v);
    default: return partner_f64<16>(v);
    }
}
__device__ inline double shfl_idx_f64(double v, int src) {
    const long long x = __double_as_longlong(v);
    const int lo = __shfl((int)(unsigned int)x, src, 64);
    const int hi = __shfl((int)(x >> 32), src, 64);
    return __longlong_as_double(((long long)hi << 32) | (unsigned int)lo);
}

// Full bitonic sort across 64 lanes (f32), ascending by lane. 21 stages.
__device__ inline float bitonic_sort64_f32(float v, int lane) {
#pragma unroll
    for (int k = 2; k <= 64; k <<= 1) {
#pragma unroll
        for (int d = k >> 1; d >= 1; d >>= 1) {
            const float o = partner_f32_dyn(v, d);
            const float mn = fminf(v, o);
            const float mx = fmaxf(v, o);
            const bool keepMin = ((lane & k) == 0) == ((lane & d) == 0);
            v = keepMin ? mn : mx;
        }
    }
    return v;
}

// Bitonic sort of 32 values held in lanes 0..31 (f64), ascending. 15 stages,
// xor distances <= 16 only (DPP + ds_swizzle; no bpermute). Lanes 32..63 sort
// a duplicate copy -- harmless.
__device__ inline double bitonic_sort32_f64(double v, int lane) {
#pragma unroll
    for (int k = 2; k <= 32; k <<= 1) {
#pragma unroll
        for (int d = k >> 1; d >= 1; d >>= 1) {
            const double o = partner_f64_dyn(v, d);
            const double mn = fmin(v, o);
            const double mx = fmax(v, o);
            const bool keepMin = ((lane & k) == 0) == ((lane & d) == 0);
            v = keepMin ? mn : mx;
        }
    }
    return v;
}

// Swizzled word index for point j within a 2048-word SoA coordinate array.
// Lane L = j>>5 owns 32 consecutive words; 4-word chunks are XOR-permuted by
// (L&7) so that ds_read_b128 across the wave is bank-conflict-free.
__device__ inline int swz(int j) {
    const int u = j & 31;
    return (j & ~31) | ((((u >> 2) ^ ((j >> 5) & 7)) << 2) | (u & 3));
}

__global__ __launch_bounds__(256, 6) void knn_kernel(
    const float* __restrict__ pts,   // [B,S,3]
    const int*   __restrict__ fidx,  // [B,S,1]
    const float* __restrict__ attr,  // [B,S,D]
    float*       __restrict__ out)   // out0 [B,S,K] | out1 [B,S,K] | out2 [B,S,K,D]
{
    __shared__ __align__(16) float sp[3 * NS];   // swizzled SoA x|y|z, 24576 B
    __shared__ double sbuf[4][32];               // per-wave survivor window

    const int tid  = threadIdx.x;
    const int wv   = tid >> 6;
    const int lane = tid & 63;
    const int row  = blockIdx.x * 4 + wv;   // 4 rows/block, same batch
    const int b = row >> 11;
    const int i = row & 2047;

    // Stage the batch's 2048 points into swizzled SoA (8 points per thread).
    {
        const float* pb = pts + (size_t)b * NS * 3;
#pragma unroll
        for (int p = 0; p < 8; ++p) {
            const int j = p * 256 + tid;
            const float x = pb[j * 3 + 0];
            const float y = pb[j * 3 + 1];
            const float z = pb[j * 3 + 2];
            const int w = swz(j);
            sp[w] = x;
            sp[NS + w] = y;
            sp[2 * NS + w] = z;
        }
    }
    __syncthreads();

    const int wi = swz(i);
    const float qx = sp[wi];
    const float qy = sp[NS + wi];
    const float qz = sp[2 * NS + wi];

    // Lane owns candidates j = lane*32 .. lane*32+31; 24 ds_read_b128 total.
    float dist[32];
    float m = 3.4e38f;
    const int base = lane * 32;
#pragma unroll
    for (int c = 0; c < 8; ++c) {
        const int slot = base + (((c ^ (lane & 7)) << 2));
        const f32x4 X = *(const f32x4*)&sp[slot];
        const f32x4 Y = *(const f32x4*)&sp[NS + slot];
        const f32x4 Z = *(const f32x4*)&sp[2 * NS + slot];
#pragma unroll
        for (int k = 0; k < 4; ++k) {
            const float dx = __fsub_rn(qx, X[k]);
            const float dy = __fsub_rn(qy, Y[k]);
            const float dz = __fsub_rn(qz, Z[k]);
            // exact left-to-right, no FMA contraction (matches reference)
            float d = __fmul_rn(dx, dx);
            d = __fadd_rn(d, __fmul_rn(dy, dy));
            d = __fadd_rn(d, __fmul_rn(dz, dz));
            dist[c * 4 + k] = d;     // candidate u = c*4+k  ->  j = base + u
            m = fminf(m, d);
        }
    }

    // T = 16th smallest lane-min: >=16 elements are <= T, so every true
    // top-16 element has dist <= T (any element > T has >=16 better ones).
    const float ms = bitonic_sort64_f32(m, lane);
    const float T = __shfl(ms, 15, 64);

    // Chunked exact selection over survivors (dist <= T). E[M] ~ 18 -> the
    // loop body usually runs once; later chunks keep it exact for any M.
    double* sw = &sbuf[wv][0];
    const double INF = __longlong_as_double(0x7FF0000000000000LL);
    double r = INF;                 // lanes 0..15: global sorted top-16 so far
    for (int c0 = 0;; c0 += 32) {
        if (lane < 32) sw[lane] = INF;
        int cnt = 0;
#pragma unroll
        for (int u = 0; u < 32; ++u) {
            const bool pred = (dist[u] <= T);
            const unsigned long long bal = __ballot(pred);
            const int rank = __builtin_amdgcn_mbcnt_hi(
                (unsigned int)(bal >> 32),
                __builtin_amdgcn_mbcnt_lo((unsigned int)bal, 0));
            const int slot = cnt + rank - c0;
            if (pred && (unsigned int)slot < 32u) {
                // Monotone f64 key: hi = dist_bits + 0x10000000 (positive
                // normal for this data's dist range), lo = j. f64 order ==
                // (dist, j) lex order; all keys distinct.
                const unsigned int hi = __float_as_uint(dist[u]) + 0x10000000u;
                const unsigned int lo = (unsigned int)(base + u);
                sw[slot] = __longlong_as_double(((long long)hi << 32) | lo);
            }
            cnt += (int)__popcll(bal);
        }
        asm volatile("s_waitcnt lgkmcnt(0)" ::: "memory");
        double v = sw[lane & 31];
        v = bitonic_sort32_f64(v, lane);
        if (c0 == 0) {
            r = v;
        } else {
            // merge-low-16: r (lanes 0..15) with v's low-16 (lanes 0..15)
            double s = shfl_idx_f64(v, (15 - lane) & 63);
            double ml = fmin(r, s);
#pragma unroll
            for (int d = 8; d >= 1; d >>= 1) {
                const double o = partner_f64_dyn(ml, d);
                const double mn = fmin(ml, o);
                const double mx = fmax(ml, o);
                ml = ((lane & d) == 0) ? mn : mx;
            }
            r = ml;
        }
        if (cnt <= c0 + 32) break;
    }

    // Decode: lane k (k<16) holds winner k.
    const long long kb = __double_as_longlong(r);
    const int jsel = (int)(unsigned int)kb;
    const unsigned int db = (unsigned int)((unsigned long long)kb >> 32) - 0x10000000u;

    float* out0 = out;                                   // [B,S,K]
    float* out1 = out + (size_t)NB * NS * NK;            // [B,S,K]
    float* out2 = out + (size_t)2 * NB * NS * NK;        // [B,S,K,D]
    const size_t rowBase = (size_t)row * NK;

    if (lane < NK) {
        out0[rowBase + lane] = __uint_as_float(db);
        const int ii = fidx[(size_t)b * NS + i];
        const int jj = fidx[(size_t)b * NS + jsel];
        out1[rowBase + lane] = fabsf((float)(ii - jj));
    }

    // Gather attribute rows: 2 neighbor rows per pass (512B each).
    const int half = lane >> 5;      // 0 or 1
    const int comp = lane & 31;      // float4 slot within the 128-float row
    const float* ab = attr + (size_t)b * NS * ND;
    float* o2row = out2 + rowBase * ND;

    int jj8[8];
#pragma unroll
    for (int p = 0; p < 8; ++p) jj8[p] = __shfl(jsel, 2 * p + half, 64);
    f32x4 v8[8];
#pragma unroll
    for (int p = 0; p < 8; ++p)
        v8[p] = *(const f32x4*)(ab + (size_t)jj8[p] * ND + comp * 4);
#pragma unroll
    for (int p = 0; p < 8; ++p)
        *(f32x4*)(o2row + (size_t)(2 * p + half) * ND + comp * 4) = v8[p];
}

extern "C" void kernel_launch(void* const* d_in, const int* in_sizes, int n_in,
                              void* d_out, int out_size, void* d_ws, size_t ws_size,
                              hipStream_t stream) {
    const float* pts  = (const float*)d_in[0];
    const int*   fidx = (const int*)d_in[1];
    const float* attr = (const float*)d_in[2];
    float* out = (float*)d_out;

    const int rows = NB * NS;                 // 16384
    const int blocks = rows / 4;              // 4096 blocks, 4 waves each
    knn_kernel<<<blocks, 256, 0, stream>>>(pts, fidx, attr, out);
}

// Round 8
// 42.815 us; speedup vs baseline: 1.4579x; 1.4579x over previous
//
#include <hip/hip_runtime.h>

#define NB 8
#define NS 2048
#define ND 128
#define NK 16

typedef float f32x4 __attribute__((ext_vector_type(4)));

// ---- cross-lane partner fetch (lane ^ KIND) ----
template <int KIND>
__device__ inline int partner_i32(int v) {
    if constexpr (KIND == 1) {
        return __builtin_amdgcn_update_dpp(0, v, 0xB1, 0xF, 0xF, true);   // quad_perm xor1
    } else if constexpr (KIND == 2) {
        return __builtin_amdgcn_update_dpp(0, v, 0x4E, 0xF, 0xF, true);   // quad_perm xor2
    } else if constexpr (KIND == 32) {
        return __shfl_xor(v, 32, 64);
    } else {
        constexpr int imm = (KIND << 10) | 0x1F;                          // ds_swizzle BitMode
        return __builtin_amdgcn_ds_swizzle(v, imm);
    }
}
template <int KIND>
__device__ inline float partner_f32(float v) {
    return __int_as_float(partner_i32<KIND>(__float_as_int(v)));
}
template <int KIND>
__device__ inline double partner_f64(double v) {
    const long long x = __double_as_longlong(v);
    const int lo = partner_i32<KIND>((int)(unsigned int)x);
    const int hi = partner_i32<KIND>((int)(x >> 32));
    return __longlong_as_double(((long long)hi << 32) | (unsigned int)lo);
}
__device__ inline float partner_f32_dyn(float v, int d) {
    switch (d) {
    case 1:  return partner_f32<1>(v);
    case 2:  return partner_f32<2>(v);
    case 4:  return partner_f32<4>(v);
    case 8:  return partner_f32<8>(v);
    case 16: return partner_f32<16>(v);
    default: return partner_f32<32>(v);
    }
}
__device__ inline double partner_f64_dyn(double v, int d) {
    switch (d) {
    case 1:  return partner_f64<1>(v);
    case 2:  return partner_f64<2>(v);
    case 4:  return partner_f64<4>(v);
    case 8:  return partner_f64<8>(v);
    default: return partner_f64<16>(v);
    }
}
__device__ inline double shfl_idx_f64(double v, int src) {
    const long long x = __double_as_longlong(v);
    const int lo = __shfl((int)(unsigned int)x, src, 64);
    const int hi = __shfl((int)(x >> 32), src, 64);
    return __longlong_as_double(((long long)hi << 32) | (unsigned int)lo);
}

// Full bitonic sort across 64 lanes (f32), ascending by lane. 21 stages.
__device__ inline float bitonic_sort64_f32(float v, int lane) {
#pragma unroll
    for (int k = 2; k <= 64; k <<= 1) {
#pragma unroll
        for (int d = k >> 1; d >= 1; d >>= 1) {
            const float o = partner_f32_dyn(v, d);
            const float mn = fminf(v, o);
            const float mx = fmaxf(v, o);
            const bool keepMin = ((lane & k) == 0) == ((lane & d) == 0);
            v = keepMin ? mn : mx;
        }
    }
    return v;
}

// Bitonic sort of 32 values held in lanes 0..31 (f64), ascending. 15 stages,
// xor distances <= 16 only (DPP + ds_swizzle; no bpermute). Lanes 32..63 sort
// a duplicate copy -- harmless.
__device__ inline double bitonic_sort32_f64(double v, int lane) {
#pragma unroll
    for (int k = 2; k <= 32; k <<= 1) {
#pragma unroll
        for (int d = k >> 1; d >= 1; d >>= 1) {
            const double o = partner_f64_dyn(v, d);
            const double mn = fmin(v, o);
            const double mx = fmax(v, o);
            const bool keepMin = ((lane & k) == 0) == ((lane & d) == 0);
            v = keepMin ? mn : mx;
        }
    }
    return v;
}

__global__ __launch_bounds__(256) void knn_kernel(
    const float* __restrict__ pts,   // [B,S,3]
    const int*   __restrict__ fidx,  // [B,S,1]
    const float* __restrict__ attr,  // [B,S,D]
    float*       __restrict__ out)   // out0 [B,S,K] | out1 [B,S,K] | out2 [B,S,K,D]
{
    __shared__ __align__(16) float sp[3 * NS];   // SoA: x[2048] | y[2048] | z[2048]
    __shared__ double sbuf[4][32];               // per-wave survivor window

    const int tid  = threadIdx.x;
    const int wv   = tid >> 6;
    const int lane = tid & 63;
    const int row  = blockIdx.x * 4 + wv;   // 4 rows/block, same batch
    const int b = row >> 11;
    const int i = row & 2047;

    // Stage batch points AoS -> SoA: per 4-point group, 3 f32x4 loads,
    // in-register transpose, 3 ds_write_b128 (coalesced / conflict-free).
    {
        const f32x4* pb4 = (const f32x4*)(pts + (size_t)b * NS * 3);
        f32x4* sx4 = (f32x4*)sp;
        f32x4* sy4 = (f32x4*)(sp + NS);
        f32x4* sz4 = (f32x4*)(sp + 2 * NS);
#pragma unroll
        for (int g0 = 0; g0 < 2; ++g0) {
            const int g = g0 * 256 + tid;            // 4-point group id, 0..511
            const f32x4 A = pb4[3 * g + 0];          // x0 y0 z0 x1
            const f32x4 Bv = pb4[3 * g + 1];         // y1 z1 x2 y2
            const f32x4 Cv = pb4[3 * g + 2];         // z2 x3 y3 z3
            f32x4 X, Y, Z;
            X[0] = A[0]; X[1] = A[3]; X[2] = Bv[2]; X[3] = Cv[1];
            Y[0] = A[1]; Y[1] = Bv[0]; Y[2] = Bv[3]; Y[3] = Cv[2];
            Z[0] = A[2]; Z[1] = Bv[1]; Z[2] = Cv[0]; Z[3] = Cv[3];
            sx4[g] = X;
            sy4[g] = Y;
            sz4[g] = Z;
        }
    }
    __syncthreads();

    const float qx = sp[i];
    const float qy = sp[NS + i];
    const float qz = sp[2 * NS + i];

    // Lane owns candidates j = c*256 + 4*lane + k (c=0..7, k=0..3):
    // 24 ds_read_b128, each wave-instruction reading a contiguous 1KB.
    float dist[32];
    float m = 3.4e38f;
    {
        const f32x4* sx4 = (const f32x4*)sp;
        const f32x4* sy4 = (const f32x4*)(sp + NS);
        const f32x4* sz4 = (const f32x4*)(sp + 2 * NS);
#pragma unroll
        for (int c = 0; c < 8; ++c) {
            const f32x4 X = sx4[c * 64 + lane];
            const f32x4 Y = sy4[c * 64 + lane];
            const f32x4 Z = sz4[c * 64 + lane];
#pragma unroll
            for (int k = 0; k < 4; ++k) {
                const float dx = __fsub_rn(qx, X[k]);
                const float dy = __fsub_rn(qy, Y[k]);
                const float dz = __fsub_rn(qz, Z[k]);
                // exact left-to-right, no FMA contraction (matches reference)
                float d = __fmul_rn(dx, dx);
                d = __fadd_rn(d, __fmul_rn(dy, dy));
                d = __fadd_rn(d, __fmul_rn(dz, dz));
                dist[c * 4 + k] = d;
                m = fminf(m, d);
            }
        }
    }

    // T = 16th smallest lane-min: 16 distinct elements (one per lane) are
    // <= T, so any element with dist > T has >=16 strictly better ones.
    const float ms = bitonic_sort64_f32(m, lane);
    const float T = __shfl(ms, 15, 64);

    // Survivor count + wave exclusive scan (placement order is irrelevant:
    // each window is fully sorted before use).
    int nl = 0;
#pragma unroll
    for (int u = 0; u < 32; ++u) nl += (dist[u] <= T) ? 1 : 0;
    int sc = nl;
#pragma unroll
    for (int d = 1; d < 64; d <<= 1) {
        const int t2 = __shfl_up(sc, d, 64);
        if (lane >= d) sc += t2;
    }
    const int M = __shfl(sc, 63, 64);   // total survivors (>= 16)
    const int myoff = sc - nl;          // exclusive offset

    // Chunked exact selection: E[M] ~ 18 -> single pass almost always.
    double* sw = &sbuf[wv][0];
    const double INF = __longlong_as_double(0x7FF0000000000000LL);
    double r = INF;                     // lanes 0..15: sorted top-16 so far
    for (int c0 = 0;; c0 += 32) {
        if (lane < 32) sw[lane] = INF;
        int off = myoff;
#pragma unroll
        for (int u = 0; u < 32; ++u) {
            const bool p = (dist[u] <= T);
            const int slot = off - c0;
            if (p && (unsigned int)slot < 32u) {
                // Monotone f64 key: hi = dist_bits + 0x10000000 (positive
                // normal), lo = j. f64 order == (dist, j) lex order.
                const unsigned int hi = __float_as_uint(dist[u]) + 0x10000000u;
                const unsigned int lo =
                    (unsigned int)((u >> 2) * 256 + 4 * lane + (u & 3));
                sw[slot] = __longlong_as_double(((long long)hi << 32) | lo);
            }
            off += p ? 1 : 0;
        }
        asm volatile("s_waitcnt lgkmcnt(0)" ::: "memory");
        double v = sw[lane & 31];
        v = bitonic_sort32_f64(v, lane);
        if (c0 == 0) {
            r = v;
        } else {
            // merge-low-16: r (lanes 0..15) with v's low-16
            double s = shfl_idx_f64(v, (15 - lane) & 63);
            double ml = fmin(r, s);
#pragma unroll
            for (int d = 8; d >= 1; d >>= 1) {
                const double o = partner_f64_dyn(ml, d);
                const double mn = fmin(ml, o);
                const double mx = fmax(ml, o);
                ml = ((lane & d) == 0) ? mn : mx;
            }
            r = ml;
        }
        if (M <= c0 + 32) break;
    }

    // Decode: lane k (k<16) holds winner k.
    const long long kb = __double_as_longlong(r);
    const int jsel = (int)(unsigned int)kb;
    const unsigned int db = (unsigned int)((unsigned long long)kb >> 32) - 0x10000000u;

    float* out0 = out;                                   // [B,S,K]
    float* out1 = out + (size_t)NB * NS * NK;            // [B,S,K]
    float* out2 = out + (size_t)2 * NB * NS * NK;        // [B,S,K,D]
    const size_t rowBase = (size_t)row * NK;

    if (lane < NK) {
        out0[rowBase + lane] = __uint_as_float(db);
        const int ii = fidx[(size_t)b * NS + i];
        const int jj = fidx[(size_t)b * NS + jsel];
        out1[rowBase + lane] = fabsf((float)(ii - jj));
    }

    // Gather attribute rows: 2 neighbor rows per pass (512B each).
    const int half = lane >> 5;      // 0 or 1
    const int comp = lane & 31;      // float4 slot within the 128-float row
    const float* ab = attr + (size_t)b * NS * ND;
    float* o2row = out2 + rowBase * ND;

    int jj8[8];
#pragma unroll
    for (int p = 0; p < 8; ++p) jj8[p] = __shfl(jsel, 2 * p + half, 64);
    f32x4 v8[8];
#pragma unroll
    for (int p = 0; p < 8; ++p)
        v8[p] = *(const f32x4*)(ab + (size_t)jj8[p] * ND + comp * 4);
#pragma unroll
    for (int p = 0; p < 8; ++p)
        *(f32x4*)(o2row + (size_t)(2 * p + half) * ND + comp * 4) = v8[p];
}

extern "C" void kernel_launch(void* const* d_in, const int* in_sizes, int n_in,
                              void* d_out, int out_size, void* d_ws, size_t ws_size,
                              hipStream_t stream) {
    const float* pts  = (const float*)d_in[0];
    const int*   fidx = (const int*)d_in[1];
    const float* attr = (const float*)d_in[2];
    float* out = (float*)d_out;

    const int rows = NB * NS;                 // 16384
    const int blocks = rows / 4;              // 4096 blocks, 4 waves each
    knn_kernel<<<blocks, 256, 0, stream>>>(pts, fidx, attr, out);
}

// Round 9
// 42.589 us; speedup vs baseline: 1.4657x; 1.0053x over previous
//
#include <hip/hip_runtime.h>

#define NB 8
#define NS 2048
#define ND 128
#define NK 16

typedef float f32x4 __attribute__((ext_vector_type(4)));

// ---- cross-lane partner fetch (lane ^ KIND) ----
template <int KIND>
__device__ inline int partner_i32(int v) {
    if constexpr (KIND == 1) {
        return __builtin_amdgcn_update_dpp(0, v, 0xB1, 0xF, 0xF, true);   // quad_perm xor1
    } else if constexpr (KIND == 2) {
        return __builtin_amdgcn_update_dpp(0, v, 0x4E, 0xF, 0xF, true);   // quad_perm xor2
    } else if constexpr (KIND == 32) {
        return __shfl_xor(v, 32, 64);
    } else {
        constexpr int imm = (KIND << 10) | 0x1F;                          // ds_swizzle BitMode
        return __builtin_amdgcn_ds_swizzle(v, imm);
    }
}
template <int KIND>
__device__ inline float partner_f32(float v) {
    return __int_as_float(partner_i32<KIND>(__float_as_int(v)));
}
template <int KIND>
__device__ inline double partner_f64(double v) {
    const long long x = __double_as_longlong(v);
    const int lo = partner_i32<KIND>((int)(unsigned int)x);
    const int hi = partner_i32<KIND>((int)(x >> 32));
    return __longlong_as_double(((long long)hi << 32) | (unsigned int)lo);
}
__device__ inline float partner_f32_dyn(float v, int d) {
    switch (d) {
    case 1:  return partner_f32<1>(v);
    case 2:  return partner_f32<2>(v);
    case 4:  return partner_f32<4>(v);
    case 8:  return partner_f32<8>(v);
    case 16: return partner_f32<16>(v);
    default: return partner_f32<32>(v);
    }
}
__device__ inline double partner_f64_dyn(double v, int d) {
    switch (d) {
    case 1:  return partner_f64<1>(v);
    case 2:  return partner_f64<2>(v);
    case 4:  return partner_f64<4>(v);
    case 8:  return partner_f64<8>(v);
    default: return partner_f64<16>(v);
    }
}
__device__ inline double shfl_idx_f64(double v, int src) {
    const long long x = __double_as_longlong(v);
    const int lo = __shfl((int)(unsigned int)x, src, 64);
    const int hi = __shfl((int)(x >> 32), src, 64);
    return __longlong_as_double(((long long)hi << 32) | (unsigned int)lo);
}

// Full bitonic sort across 64 lanes (f32), ascending by lane. 21 stages.
__device__ inline float bitonic_sort64_f32(float v, int lane) {
#pragma unroll
    for (int k = 2; k <= 64; k <<= 1) {
#pragma unroll
        for (int d = k >> 1; d >= 1; d >>= 1) {
            const float o = partner_f32_dyn(v, d);
            const float mn = fminf(v, o);
            const float mx = fmaxf(v, o);
            const bool keepMin = ((lane & k) == 0) == ((lane & d) == 0);
            v = keepMin ? mn : mx;
        }
    }
    return v;
}

// Bitonic sort of 32 values held in lanes 0..31 (f64), ascending. 15 stages,
// xor distances <= 16 only (DPP + ds_swizzle; no bpermute). Lanes 32..63 sort
// a duplicate copy -- harmless.
__device__ inline double bitonic_sort32_f64(double v, int lane) {
#pragma unroll
    for (int k = 2; k <= 32; k <<= 1) {
#pragma unroll
        for (int d = k >> 1; d >= 1; d >>= 1) {
            const double o = partner_f64_dyn(v, d);
            const double mn = fmin(v, o);
            const double mx = fmax(v, o);
            const bool keepMin = ((lane & k) == 0) == ((lane & d) == 0);
            v = keepMin ? mn : mx;
        }
    }
    return v;
}

__global__ __launch_bounds__(256) void knn_kernel(
    const float* __restrict__ pts,   // [B,S,3]
    const int*   __restrict__ fidx,  // [B,S,1]
    const float* __restrict__ attr,  // [B,S,D]
    float*       __restrict__ out)   // out0 [B,S,K] | out1 [B,S,K] | out2 [B,S,K,D]
{
    __shared__ __align__(16) float sp[3 * NS];   // SoA: x[2048] | y[2048] | z[2048]
    __shared__ double sbuf[4][32];               // per-wave survivor window

    const int tid  = threadIdx.x;
    const int wv   = tid >> 6;
    const int lane = tid & 63;
    const int row  = blockIdx.x * 4 + wv;   // 4 rows/block, same batch
    const int b = row >> 11;
    const int i = row & 2047;

    // Stage batch points AoS -> SoA: per 4-point group, 3 f32x4 loads,
    // in-register transpose, 3 ds_write_b128 (coalesced / conflict-free).
    {
        const f32x4* pb4 = (const f32x4*)(pts + (size_t)b * NS * 3);
        f32x4* sx4 = (f32x4*)sp;
        f32x4* sy4 = (f32x4*)(sp + NS);
        f32x4* sz4 = (f32x4*)(sp + 2 * NS);
#pragma unroll
        for (int g0 = 0; g0 < 2; ++g0) {
            const int g = g0 * 256 + tid;            // 4-point group id, 0..511
            const f32x4 A = pb4[3 * g + 0];          // x0 y0 z0 x1
            const f32x4 Bv = pb4[3 * g + 1];         // y1 z1 x2 y2
            const f32x4 Cv = pb4[3 * g + 2];         // z2 x3 y3 z3
            f32x4 X, Y, Z;
            X[0] = A[0]; X[1] = A[3]; X[2] = Bv[2]; X[3] = Cv[1];
            Y[0] = A[1]; Y[1] = Bv[0]; Y[2] = Bv[3]; Y[3] = Cv[2];
            Z[0] = A[2]; Z[1] = Bv[1]; Z[2] = Cv[0]; Z[3] = Cv[3];
            sx4[g] = X;
            sy4[g] = Y;
            sz4[g] = Z;
        }
    }
    __syncthreads();

    const float qx = sp[i];
    const float qy = sp[NS + i];
    const float qz = sp[2 * NS + i];

    // Lane owns candidates j = c*256 + 4*lane + k (c=0..7, k=0..3):
    // 24 ds_read_b128, each wave-instruction reading a contiguous 1KB.
    float dist[32];
    float m = 3.4e38f;
    {
        const f32x4* sx4 = (const f32x4*)sp;
        const f32x4* sy4 = (const f32x4*)(sp + NS);
        const f32x4* sz4 = (const f32x4*)(sp + 2 * NS);
#pragma unroll
        for (int c = 0; c < 8; ++c) {
            const f32x4 X = sx4[c * 64 + lane];
            const f32x4 Y = sy4[c * 64 + lane];
            const f32x4 Z = sz4[c * 64 + lane];
#pragma unroll
            for (int k = 0; k < 4; ++k) {
                const float dx = __fsub_rn(qx, X[k]);
                const float dy = __fsub_rn(qy, Y[k]);
                const float dz = __fsub_rn(qz, Z[k]);
                // exact left-to-right, no FMA contraction (matches reference)
                float d = __fmul_rn(dx, dx);
                d = __fadd_rn(d, __fmul_rn(dy, dy));
                d = __fadd_rn(d, __fmul_rn(dz, dz));
                dist[c * 4 + k] = d;
                m = fminf(m, d);
            }
        }
    }

    // T = 16th smallest lane-min: 16 distinct elements (one per lane) are
    // <= T, so any element with dist > T has >=16 strictly better ones.
    const float ms = bitonic_sort64_f32(m, lane);
    const float T = __shfl(ms, 15, 64);

    // Survivor count + wave exclusive scan (placement order is irrelevant:
    // each window is fully sorted before use).
    int nl = 0;
#pragma unroll
    for (int u = 0; u < 32; ++u) nl += (dist[u] <= T) ? 1 : 0;
    int sc = nl;
#pragma unroll
    for (int d = 1; d < 64; d <<= 1) {
        const int t2 = __shfl_up(sc, d, 64);
        if (lane >= d) sc += t2;
    }
    const int M = __shfl(sc, 63, 64);   // total survivors (>= 16)
    const int myoff = sc - nl;          // exclusive offset

    // Chunked exact selection: E[M] ~ 18 -> single pass almost always.
    double* sw = &sbuf[wv][0];
    const double INF = __longlong_as_double(0x7FF0000000000000LL);
    double r = INF;                     // lanes 0..15: sorted top-16 so far
    for (int c0 = 0;; c0 += 32) {
        if (lane < 32) sw[lane] = INF;
        int off = myoff;
#pragma unroll
        for (int u = 0; u < 32; ++u) {
            const bool p = (dist[u] <= T);
            const int slot = off - c0;
            if (p && (unsigned int)slot < 32u) {
                // Monotone f64 key: hi = dist_bits + 0x10000000 (positive
                // normal), lo = j. f64 order == (dist, j) lex order.
                const unsigned int hi = __float_as_uint(dist[u]) + 0x10000000u;
                const unsigned int lo =
                    (unsigned int)((u >> 2) * 256 + 4 * lane + (u & 3));
                sw[slot] = __longlong_as_double(((long long)hi << 32) | lo);
            }
            off += p ? 1 : 0;
        }
        asm volatile("s_waitcnt lgkmcnt(0)" ::: "memory");
        double v = sw[lane & 31];
        v = bitonic_sort32_f64(v, lane);
        if (c0 == 0) {
            r = v;
        } else {
            // merge-low-16: r (lanes 0..15) with v's low-16
            double s = shfl_idx_f64(v, (15 - lane) & 63);
            double ml = fmin(r, s);
#pragma unroll
            for (int d = 8; d >= 1; d >>= 1) {
                const double o = partner_f64_dyn(ml, d);
                const double mn = fmin(ml, o);
                const double mx = fmax(ml, o);
                ml = ((lane & d) == 0) ? mn : mx;
            }
            r = ml;
        }
        if (M <= c0 + 32) break;
    }

    // Decode: lane k (k<16) holds winner k.
    const long long kb = __double_as_longlong(r);
    const int jsel = (int)(unsigned int)kb;
    const unsigned int db = (unsigned int)((unsigned long long)kb >> 32) - 0x10000000u;

    float* out0 = out;                                   // [B,S,K]
    float* out1 = out + (size_t)NB * NS * NK;            // [B,S,K]
    float* out2 = out + (size_t)2 * NB * NS * NK;        // [B,S,K,D]
    const size_t rowBase = (size_t)row * NK;

    if (lane < NK) {
        out0[rowBase + lane] = __uint_as_float(db);
        const int ii = fidx[(size_t)b * NS + i];
        const int jj = fidx[(size_t)b * NS + jsel];
        out1[rowBase + lane] = fabsf((float)(ii - jj));
    }

    // Gather attribute rows: 2 neighbor rows per pass (512B each).
    // 4-deep load/store pipeline (2 passes) to cut live VGPRs; non-temporal
    // stores keep the never-re-read 128MB out2 stream out of L2 so the attr
    // table (8.4MB) stays L2-resident.
    const int half = lane >> 5;      // 0 or 1
    const int comp = lane & 31;      // float4 slot within the 128-float row
    const float* ab = attr + (size_t)b * NS * ND;
    float* o2row = out2 + rowBase * ND;

    int jj8[8];
#pragma unroll
    for (int p = 0; p < 8; ++p) jj8[p] = __shfl(jsel, 2 * p + half, 64);
#pragma unroll
    for (int h = 0; h < 2; ++h) {
        f32x4 v4[4];
#pragma unroll
        for (int q = 0; q < 4; ++q)
            v4[q] = *(const f32x4*)(ab + (size_t)jj8[h * 4 + q] * ND + comp * 4);
#pragma unroll
        for (int q = 0; q < 4; ++q)
            __builtin_nontemporal_store(
                v4[q],
                (f32x4*)(o2row + (size_t)(2 * (h * 4 + q) + half) * ND + comp * 4));
    }
}

extern "C" void kernel_launch(void* const* d_in, const int* in_sizes, int n_in,
                              void* d_out, int out_size, void* d_ws, size_t ws_size,
                              hipStream_t stream) {
    const float* pts  = (const float*)d_in[0];
    const int*   fidx = (const int*)d_in[1];
    const float* attr = (const float*)d_in[2];
    float* out = (float*)d_out;

    const int rows = NB * NS;                 // 16384
    const int blocks = rows / 4;              // 4096 blocks, 4 waves each
    knn_kernel<<<blocks, 256, 0, stream>>>(pts, fidx, attr, out);
}

// Round 11
// 39.880 us; speedup vs baseline: 1.5652x; 1.0679x over previous
//
#include <hip/hip_runtime.h>

#define NB 8
#define NS 2048
#define ND 128
#define NK 16

typedef float f32x4 __attribute__((ext_vector_type(4)));

// ---- cross-lane partner fetch (lane ^ KIND) ----
template <int KIND>
__device__ inline int partner_i32(int v) {
    if constexpr (KIND == 1) {
        return __builtin_amdgcn_update_dpp(0, v, 0xB1, 0xF, 0xF, true);   // quad_perm xor1
    } else if constexpr (KIND == 2) {
        return __builtin_amdgcn_update_dpp(0, v, 0x4E, 0xF, 0xF, true);   // quad_perm xor2
    } else if constexpr (KIND == 32) {
        return __shfl_xor(v, 32, 64);
    } else {
        constexpr int imm = (KIND << 10) | 0x1F;                          // ds_swizzle BitMode
        return __builtin_amdgcn_ds_swizzle(v, imm);
    }
}
template <int KIND>
__device__ inline float partner_f32(float v) {
    return __int_as_float(partner_i32<KIND>(__float_as_int(v)));
}
template <int KIND>
__device__ inline double partner_f64(double v) {
    const long long x = __double_as_longlong(v);
    const int lo = partner_i32<KIND>((int)(unsigned int)x);
    const int hi = partner_i32<KIND>((int)(x >> 32));
    return __longlong_as_double(((long long)hi << 32) | (unsigned int)lo);
}
__device__ inline float partner_f32_dyn(float v, int d) {
    switch (d) {
    case 1:  return partner_f32<1>(v);
    case 2:  return partner_f32<2>(v);
    case 4:  return partner_f32<4>(v);
    case 8:  return partner_f32<8>(v);
    case 16: return partner_f32<16>(v);
    default: return partner_f32<32>(v);
    }
}
__device__ inline double partner_f64_dyn(double v, int d) {
    switch (d) {
    case 1:  return partner_f64<1>(v);
    case 2:  return partner_f64<2>(v);
    case 4:  return partner_f64<4>(v);
    case 8:  return partner_f64<8>(v);
    case 16: return partner_f64<16>(v);
    default: return partner_f64<32>(v);
    }
}
__device__ inline double shfl_idx_f64(double v, int src) {
    const long long x = __double_as_longlong(v);
    const int lo = __shfl((int)(unsigned int)x, src, 64);
    const int hi = __shfl((int)(x >> 32), src, 64);
    return __longlong_as_double(((long long)hi << 32) | (unsigned int)lo);
}

// Full bitonic sort across 64 lanes, ascending by lane. 21 stages.
__device__ inline float bitonic_sort64_f32(float v, int lane) {
#pragma unroll
    for (int k = 2; k <= 64; k <<= 1) {
#pragma unroll
        for (int d = k >> 1; d >= 1; d >>= 1) {
            const float o = partner_f32_dyn(v, d);
            const float mn = fminf(v, o);
            const float mx = fmaxf(v, o);
            const bool keepMin = ((lane & k) == 0) == ((lane & d) == 0);
            v = keepMin ? mn : mx;
        }
    }
    return v;
}
__device__ inline double bitonic_sort64_f64(double v, int lane) {
#pragma unroll
    for (int k = 2; k <= 64; k <<= 1) {
#pragma unroll
        for (int d = k >> 1; d >= 1; d >>= 1) {
            const double o = partner_f64_dyn(v, d);
            const double mn = fmin(v, o);
            const double mx = fmax(v, o);
            const bool keepMin = ((lane & k) == 0) == ((lane & d) == 0);
            v = keepMin ? mn : mx;
        }
    }
    return v;
}

__global__ __launch_bounds__(256) void knn_kernel(
    const float* __restrict__ pts,   // [B,S,3]
    const int*   __restrict__ fidx,  // [B,S,1]
    const float* __restrict__ attr,  // [B,S,D]
    float*       __restrict__ out)   // out0 [B,S,K] | out1 [B,S,K] | out2 [B,S,K,D]
{
    __shared__ float spts[NS * 3];        // 24576 B: the block's batch points
    __shared__ double sbuf[4][66];        // per-wave survivor window [0..63] + dump [64]

    const int tid  = threadIdx.x;
    const int wv   = tid >> 6;
    const int lane = tid & 63;
    // XCD-aware chunked swizzle (bijective, 4096 % 8 == 0): consecutive
    // blocks on one XCD now share the SAME batch -> its 8.4MB attr table is
    // the only gather working set for that XCD's L2 (vs all 8 tables).
    const int bid  = blockIdx.x;
    const int sbid = (bid & 7) * 512 + (bid >> 3);
    const int row  = sbid * 4 + wv;       // 4 rows/block, same batch
    const int b = row >> 11;
    const int i = row & 2047;

    // Stage the batch's 2048 points (24 KB) into LDS, coalesced f32x4.
    {
        const f32x4* src = (const f32x4*)(pts + (size_t)b * NS * 3);
        f32x4* dst = (f32x4*)spts;
#pragma unroll
        for (int k = 0; k < 6; ++k) dst[k * 256 + tid] = src[k * 256 + tid];
    }
    __syncthreads();

    const float qx = spts[i * 3 + 0];
    const float qy = spts[i * 3 + 1];
    const float qz = spts[i * 3 + 2];

    // Per-lane distances for j = t*64 + lane; track lane min.
    float dist[32];
    float m = 3.4e38f;
#pragma unroll
    for (int t = 0; t < 32; ++t) {
        const int j = t * 64 + lane;
        const float x = spts[j * 3 + 0];
        const float y = spts[j * 3 + 1];
        const float z = spts[j * 3 + 2];
        const float dx = __fsub_rn(qx, x);
        const float dy = __fsub_rn(qy, y);
        const float dz = __fsub_rn(qz, z);
        // exact left-to-right, no FMA contraction (matches reference arithmetic)
        float d = __fmul_rn(dx, dx);
        d = __fadd_rn(d, __fmul_rn(dy, dy));
        d = __fadd_rn(d, __fmul_rn(dz, dz));
        dist[t] = d;
        m = fminf(m, d);
    }

    // T = 16th smallest lane-min. The 16 lanes with smallest minima each hold
    // >=1 distinct element <= T, so every true top-16 element has dist <= T.
    const float ms = bitonic_sort64_f32(m, lane);
    const float T = __shfl(ms, 15, 64);

    // Chunked exact selection over survivors (dist <= T). Expected M ~ 18,
    // so the loop runs once; the windowed re-compaction keeps it exact for
    // any M. dist[] stored once and reused -> no recompute bit-identity risk.
    double* sw = &sbuf[wv][0];
    const double INF = __longlong_as_double(0x7FF0000000000000LL);
    double r = INF;                 // lanes 0..15: global sorted top-16 so far
    for (int c0 = 0;; c0 += 64) {
        sw[lane] = INF;             // init window (in-order LDS per wave)
        int base = 0;
#pragma unroll
        for (int t = 0; t < 32; ++t) {
            const bool pred = (dist[t] <= T);
            const unsigned long long bal = __ballot(pred);
            const int rank = __builtin_amdgcn_mbcnt_hi(
                (unsigned int)(bal >> 32),
                __builtin_amdgcn_mbcnt_lo((unsigned int)bal, 0));
            const int slot = base + rank;
            const bool inw = pred && ((unsigned int)(slot - c0) < 64u);
            // Monotone f64 key: hi = dist_bits + 0x10000000 (positive normal),
            // lo = j. f64 order == (dist, j) lex order; all keys distinct.
            const unsigned int hi = __float_as_uint(dist[t]) + 0x10000000u;
            const unsigned int lo = (unsigned int)(t * 64) | (unsigned int)lane;
            const double kd = __longlong_as_double(((long long)hi << 32) | lo);
            sw[inw ? (slot - c0) : 64] = kd;
            base += (int)__popcll(bal);
        }
        const int M = base;         // wave-uniform total survivor count (>= 16)
        asm volatile("s_waitcnt lgkmcnt(0)" ::: "memory");
        double v = sw[lane];
        v = bitonic_sort64_f64(v, lane);
        if (c0 == 0) {
            r = v;
        } else {
            // merge-low-16: r(16, lanes 0..15) with v's low-16 (lanes 0..15)
            double s = shfl_idx_f64(v, (15 - lane) & 63);
            double ml = fmin(r, s);
#pragma unroll
            for (int d = 8; d >= 1; d >>= 1) {
                const double o = partner_f64_dyn(ml, d);
                const double mn = fmin(ml, o);
                const double mx = fmax(ml, o);
                ml = ((lane & d) == 0) ? mn : mx;
            }
            r = ml;
        }
        if (M <= c0 + 64) break;
    }

    // Decode: lane k (k<16) holds winner k.
    const long long kb = __double_as_longlong(r);
    const int jsel = (int)(unsigned int)kb;                       // low word = j
    const unsigned int db = (unsigned int)((unsigned long long)kb >> 32) - 0x10000000u;

    float* out0 = out;                                   // [B,S,K]
    float* out1 = out + (size_t)NB * NS * NK;            // [B,S,K]
    float* out2 = out + (size_t)2 * NB * NS * NK;        // [B,S,K,D]
    const size_t rowBase = (size_t)row * NK;

    if (lane < NK) {
        out0[rowBase + lane] = __uint_as_float(db);
        const int ii = fidx[(size_t)b * NS + i];
        const int jj = fidx[(size_t)b * NS + jsel];
        out1[rowBase + lane] = fabsf((float)(ii - jj));
    }

    // Gather attribute rows: 2 neighbor rows per pass (512B each);
    // 8 loads in flight, then 8 stores.
    const int half = lane >> 5;      // 0 or 1
    const int comp = lane & 31;      // float4 slot within the 128-float row
    const float* ab = attr + (size_t)b * NS * ND;
    float* o2row = out2 + rowBase * ND;

    int jj8[8];
#pragma unroll
    for (int p = 0; p < 8; ++p) jj8[p] = __shfl(jsel, 2 * p + half, 64);
    f32x4 v8[8];
#pragma unroll
    for (int p = 0; p < 8; ++p)
        v8[p] = *(const f32x4*)(ab + (size_t)jj8[p] * ND + comp * 4);
#pragma unroll
    for (int p = 0; p < 8; ++p)
        *(f32x4*)(o2row + (size_t)(2 * p + half) * ND + comp * 4) = v8[p];
}

extern "C" void kernel_launch(void* const* d_in, const int* in_sizes, int n_in,
                              void* d_out, int out_size, void* d_ws, size_t ws_size,
                              hipStream_t stream) {
    const float* pts  = (const float*)d_in[0];
    const int*   fidx = (const int*)d_in[1];
    const float* attr = (const float*)d_in[2];
    float* out = (float*)d_out;

    const int rows = NB * NS;                 // 16384
    const int blocks = rows / 4;              // 4096 blocks, 4 waves each
    knn_kernel<<<blocks, 256, 0, stream>>>(pts, fidx, attr, out);
}